// Round 3
// baseline (877.806 us; speedup 1.0000x reference)
//
#include <hip/hip_runtime.h>
#include <math.h>
#include <float.h>

#define N_NODES 10000
#define NFEAT   512
#define NHID    256
#define NCLASS  16
#define CAP     128   // max nnz/row; mean=51, sd=7.1 -> 128 is ~11 sigma

// ---------------- wave helpers (wave64) ----------------
__device__ __forceinline__ float wave_sum(float v) {
#pragma unroll
  for (int o = 32; o > 0; o >>= 1) v += __shfl_down(v, o, 64);
  return v;
}
__device__ __forceinline__ float wave_max(float v) {
#pragma unroll
  for (int o = 32; o > 0; o >>= 1) v = fmaxf(v, __shfl_down(v, o, 64));
  return v;
}

// ---------------- tiled f32 GEMM: C[M,N] = A[M,K] @ B[K,N] ----------------
// 64x64 tile, 256 threads, 4x4 microtile, KT=16. N must be multiple of 64,
// K multiple of 16. Row guard on A/C only.
__global__ __launch_bounds__(256) void gemm64(const float* __restrict__ A,
                                              const float* __restrict__ B,
                                              float* __restrict__ C,
                                              int M, int K, int N) {
  __shared__ float As[16][68];
  __shared__ float Bs[16][68];
  const int tid  = threadIdx.x;
  const int row0 = blockIdx.x * 64;
  const int col0 = blockIdx.y * 64;
  const int ty = tid >> 4, tx = tid & 15;
  const int arow = tid >> 2;          // 0..63
  const int akq  = (tid & 3) << 2;    // 0,4,8,12
  const int brow = tid >> 4;          // 0..15
  const int bcol = (tid & 15) << 2;   // 0..60

  float acc[4][4] = {};
  for (int k0 = 0; k0 < K; k0 += 16) {
    float4 av = make_float4(0.f, 0.f, 0.f, 0.f);
    const int gr = row0 + arow;
    if (gr < M) av = *(const float4*)&A[(size_t)gr * K + k0 + akq];
    As[akq + 0][arow] = av.x;
    As[akq + 1][arow] = av.y;
    As[akq + 2][arow] = av.z;
    As[akq + 3][arow] = av.w;
    const float4 bv = *(const float4*)&B[(size_t)(k0 + brow) * N + col0 + bcol];
    *(float4*)&Bs[brow][bcol] = bv;
    __syncthreads();
#pragma unroll
    for (int k = 0; k < 16; ++k) {
      const float4 a = *(const float4*)&As[k][ty << 2];
      const float4 b = *(const float4*)&Bs[k][tx << 2];
      acc[0][0] += a.x * b.x; acc[0][1] += a.x * b.y; acc[0][2] += a.x * b.z; acc[0][3] += a.x * b.w;
      acc[1][0] += a.y * b.x; acc[1][1] += a.y * b.y; acc[1][2] += a.y * b.z; acc[1][3] += a.y * b.w;
      acc[2][0] += a.z * b.x; acc[2][1] += a.z * b.y; acc[2][2] += a.z * b.z; acc[2][3] += a.z * b.w;
      acc[3][0] += a.w * b.x; acc[3][1] += a.w * b.y; acc[3][2] += a.w * b.z; acc[3][3] += a.w * b.w;
    }
    __syncthreads();
  }
#pragma unroll
  for (int j = 0; j < 4; ++j) {
    const int gr = row0 + (ty << 2) + j;
    if (gr < M) {
      const float4 o = make_float4(acc[j][0], acc[j][1], acc[j][2], acc[j][3]);
      *(float4*)&C[(size_t)gr * N + col0 + (tx << 2)] = o;
    }
  }
}

// ---------------- Mm = Wq @ Wk^T  (256x256, trivial cost) ----------------
__global__ __launch_bounds__(256) void wqwkT(const float* __restrict__ Wq,
                                             const float* __restrict__ Wk,
                                             float* __restrict__ Mm) {
  __shared__ float qr[NHID];
  const int a = blockIdx.x, tid = threadIdx.x;
  qr[tid] = Wq[a * NHID + tid];
  __syncthreads();
  const float* kb = &Wk[(size_t)tid * NHID];
  float acc = 0.f;
#pragma unroll 8
  for (int c = 0; c < NHID; ++c) acc += qr[c] * kb[c];
  Mm[a * NHID + tid] = acc;
}

// ------- scan adj row -> sorted CSR; fused h = relu(adj_sp @ xW1 + b1) ----
// Rank-sort makes edge order deterministic (ascending col) for replay-stable
// fp accumulation and better gather locality downstream.
__global__ __launch_bounds__(256) void scan_build(const float* __restrict__ adj,
                                                  const float* __restrict__ xW1,
                                                  const float* __restrict__ b1,
                                                  int* __restrict__ cols,
                                                  float* __restrict__ vals,
                                                  int* __restrict__ nnz,
                                                  float* __restrict__ h) {
  __shared__ int   lcols[CAP];
  __shared__ float lvals[CAP];
  __shared__ int   scols[CAP];
  __shared__ float svals[CAP];
  __shared__ int   cnt;
  const int row = blockIdx.x, tid = threadIdx.x;
  if (tid == 0) cnt = 0;
  __syncthreads();
  const float4* arow = (const float4*)&adj[(size_t)row * N_NODES];
  for (int v = tid; v < N_NODES / 4; v += 256) {
    const float4 f = arow[v];
    if (f.x != 0.f) { int p = atomicAdd(&cnt, 1); if (p < CAP) { lcols[p] = 4 * v + 0; lvals[p] = f.x; } }
    if (f.y != 0.f) { int p = atomicAdd(&cnt, 1); if (p < CAP) { lcols[p] = 4 * v + 1; lvals[p] = f.y; } }
    if (f.z != 0.f) { int p = atomicAdd(&cnt, 1); if (p < CAP) { lcols[p] = 4 * v + 2; lvals[p] = f.z; } }
    if (f.w != 0.f) { int p = atomicAdd(&cnt, 1); if (p < CAP) { lcols[p] = 4 * v + 3; lvals[p] = f.w; } }
  }
  __syncthreads();
  const int c = min(cnt, CAP);
  // parallel rank-sort (cols are distinct): thread tid places its element
  int myc = 0; float myv = 0.f; int rank = 0;
  if (tid < c) {
    myc = lcols[tid]; myv = lvals[tid];
    for (int e = 0; e < c; ++e) rank += (lcols[e] < myc);
  }
  __syncthreads();
  if (tid < c) { scols[rank] = myc; svals[rank] = myv; }
  __syncthreads();
  if (tid == 0) nnz[row] = c;
  if (tid < c) {
    cols[(size_t)row * CAP + tid] = scols[tid];
    vals[(size_t)row * CAP + tid] = svals[tid];
  }
  // h row: thread tid handles feature tid
  float acc = b1[tid];
  for (int e = 0; e < c; ++e)
    acc += svals[e] * xW1[(size_t)scols[e] * NHID + tid];
  h[(size_t)row * NHID + tid] = fmaxf(acc, 0.f);
}

// ------- fused: edge scores + masked softmax + CRF iter 1 (outp == h) -----
// score_e = t[i].h[j] / sqrt(256); attn row kept in LDS and consumed at once.
__global__ __launch_bounds__(256) void attn_crf1(const float* __restrict__ t,
                                                 const float* __restrict__ h,
                                                 const int* __restrict__ cols,
                                                 const int* __restrict__ nnz,
                                                 float* __restrict__ attn,
                                                 float* __restrict__ outn,
                                                 const float* __restrict__ alpha_p,
                                                 const float* __restrict__ beta_p) {
  __shared__ float s[CAP];
  __shared__ int   lcols[CAP];
  __shared__ float lv[CAP];
  __shared__ float red[4], red2[4];
  const int row = blockIdx.x, tid = threadIdx.x;
  const int lane = tid & 63, wv = tid >> 6;
  const int c = nnz[row];
  if (tid < c) lcols[tid] = cols[(size_t)row * CAP + tid];
  const float4 tq = *(const float4*)&t[(size_t)row * NHID + (lane << 2)];
  __syncthreads();
  for (int e = wv; e < c; e += 4) {
    const float4 kq = *(const float4*)&h[(size_t)lcols[e] * NHID + (lane << 2)];
    float p = tq.x * kq.x + tq.y * kq.y + tq.z * kq.z + tq.w * kq.w;
    p = wave_sum(p);
    if (lane == 0) s[e] = p * 0.0625f;  // 1/sqrt(256)
  }
  __syncthreads();
  float m = (tid < c) ? s[tid] : -FLT_MAX;
  m = wave_max(m);
  if (lane == 0) red[wv] = m;
  __syncthreads();
  m = fmaxf(fmaxf(red[0], red[1]), fmaxf(red[2], red[3]));
  const float ev = (tid < c) ? expf(s[tid] - m) : 0.f;
  float sum = wave_sum(ev);
  if (lane == 0) red2[wv] = sum;
  __syncthreads();
  sum = red2[0] + red2[1] + red2[2] + red2[3];
  if (tid < c) {
    const float a = ev / sum;
    attn[(size_t)row * CAP + tid] = a;
    lv[tid] = a;
  }
  __syncthreads();
  // CRF iter 1: outn = (alpha*h + beta*(attn_sp @ h)) / (alpha+beta)
  float acc = 0.f;
  for (int e = 0; e < c; ++e)
    acc += lv[e] * h[(size_t)lcols[e] * NHID + tid];
  const float a = alpha_p[0], b = beta_p[0];
  outn[(size_t)row * NHID + tid] =
      (a * h[(size_t)row * NHID + tid] + b * acc) / (a + b);
}

// ------- one CRF mean-field iter: outn = (a*h + b*(attn_sp @ outp))/(a+b) --
__global__ __launch_bounds__(256) void crf_iter(const float* __restrict__ h,
                                                const float* __restrict__ attn,
                                                const int* __restrict__ cols,
                                                const int* __restrict__ nnz,
                                                const float* __restrict__ outp,
                                                float* __restrict__ outn,
                                                const float* __restrict__ alpha_p,
                                                const float* __restrict__ beta_p) {
  __shared__ int   lcols[CAP];
  __shared__ float lv[CAP];
  const int row = blockIdx.x, tid = threadIdx.x;
  const int c = nnz[row];
  if (tid < c) {
    lcols[tid] = cols[(size_t)row * CAP + tid];
    lv[tid]    = attn[(size_t)row * CAP + tid];
  }
  __syncthreads();
  float acc = 0.f;
  for (int e = 0; e < c; ++e)
    acc += lv[e] * outp[(size_t)lcols[e] * NHID + tid];
  const float a = alpha_p[0], b = beta_p[0];
  outn[(size_t)row * NHID + tid] =
      (a * h[(size_t)row * NHID + tid] + b * acc) / (a + b);
}

// ------- fused: CRF iter 3 + LayerNorm + z = v @ W2  ([N,16]) -------------
__global__ __launch_bounds__(256) void crf_ln_w2(const float* __restrict__ h,
                                                 const float* __restrict__ attn,
                                                 const int* __restrict__ cols,
                                                 const int* __restrict__ nnz,
                                                 const float* __restrict__ outp,
                                                 const float* __restrict__ alpha_p,
                                                 const float* __restrict__ beta_p,
                                                 const float* __restrict__ lnw,
                                                 const float* __restrict__ lnb,
                                                 const float* __restrict__ W2,
                                                 float* __restrict__ z) {
  __shared__ int   lcols[CAP];
  __shared__ float lv[CAP];
  __shared__ float r1[4], r2[4], vs[NHID];
  __shared__ float part[16][17];
  const int row = blockIdx.x, tid = threadIdx.x;
  const int lane = tid & 63, wv = tid >> 6;
  const int c = nnz[row];
  if (tid < c) {
    lcols[tid] = cols[(size_t)row * CAP + tid];
    lv[tid]    = attn[(size_t)row * CAP + tid];
  }
  __syncthreads();
  float acc = 0.f;
  for (int e = 0; e < c; ++e)
    acc += lv[e] * outp[(size_t)lcols[e] * NHID + tid];
  const float a = alpha_p[0], b = beta_p[0];
  const float x = (a * h[(size_t)row * NHID + tid] + b * acc) / (a + b);
  // LayerNorm over the row (never touches HBM)
  float s = wave_sum(x);
  if (lane == 0) r1[wv] = s;
  __syncthreads();
  const float mu = (r1[0] + r1[1] + r1[2] + r1[3]) * (1.f / NHID);
  const float d = x - mu;
  float s2 = wave_sum(d * d);
  if (lane == 0) r2[wv] = s2;
  __syncthreads();
  const float var = (r2[0] + r2[1] + r2[2] + r2[3]) * (1.f / NHID);
  const float v = d * rsqrtf(var + 1e-5f) * lnw[tid] + lnb[tid];
  vs[tid] = v;
  __syncthreads();
  const int cc = tid & 15, g = tid >> 4;
  float p = 0.f;
#pragma unroll
  for (int u = 0; u < 16; ++u)
    p += vs[(g << 4) + u] * W2[((g << 4) + u) * NCLASS + cc];
  part[g][cc] = p;
  __syncthreads();
  if (tid < NCLASS) {
    float q = 0.f;
#pragma unroll
    for (int g2 = 0; g2 < 16; ++g2) q += part[g2][tid];
    z[(size_t)row * NCLASS + tid] = q;
  }
}

// ------- y = adj_sp @ z + b2, then log_softmax over 16 classes -------
__global__ __launch_bounds__(256) void final_k(const float* __restrict__ z,
                                               const float* __restrict__ vals,
                                               const int* __restrict__ cols,
                                               const int* __restrict__ nnz,
                                               const float* __restrict__ b2,
                                               float* __restrict__ out) {
  __shared__ int   lcols[CAP];
  __shared__ float lv[CAP];
  __shared__ float part[16][17];
  __shared__ float ys[16];
  const int row = blockIdx.x, tid = threadIdx.x;
  const int c = nnz[row];
  if (tid < c) {
    lcols[tid] = cols[(size_t)row * CAP + tid];
    lv[tid]    = vals[(size_t)row * CAP + tid];
  }
  __syncthreads();
  const int cc = tid & 15, g = tid >> 4;
  float acc = 0.f;
  for (int e = g; e < c; e += 16)
    acc += lv[e] * z[(size_t)lcols[e] * NCLASS + cc];
  part[g][cc] = acc;
  __syncthreads();
  if (tid < NCLASS) {
    float y = b2[tid];
#pragma unroll
    for (int g2 = 0; g2 < 16; ++g2) y += part[g2][tid];
    ys[tid] = y;
  }
  __syncthreads();
  if (tid < NCLASS) {
    float m = ys[0];
#pragma unroll
    for (int i = 1; i < 16; ++i) m = fmaxf(m, ys[i]);
    float ssum = 0.f;
#pragma unroll
    for (int i = 0; i < 16; ++i) ssum += expf(ys[i] - m);
    out[(size_t)row * NCLASS + tid] = ys[tid] - m - logf(ssum);
  }
}

extern "C" void kernel_launch(void* const* d_in, const int* in_sizes, int n_in,
                              void* d_out, int out_size, void* d_ws, size_t ws_size,
                              hipStream_t stream) {
  const float* x   = (const float*)d_in[0];
  const float* adj = (const float*)d_in[1];
  const float* W1  = (const float*)d_in[2];
  const float* b1  = (const float*)d_in[3];
  const float* Wq  = (const float*)d_in[4];
  const float* Wk  = (const float*)d_in[5];
  const float* al  = (const float*)d_in[6];
  const float* be  = (const float*)d_in[7];
  const float* lnw = (const float*)d_in[8];
  const float* lnb = (const float*)d_in[9];
  const float* W2  = (const float*)d_in[10];
  const float* b2  = (const float*)d_in[11];
  float* out = (float*)d_out;

  char* w = (char*)d_ws;
  size_t off = 0;
  auto alloc = [&](size_t bytes) -> void* {
    void* p = (void*)(w + off);
    off += (bytes + 255) & ~(size_t)255;
    return p;
  };
  float* bufA = (float*)alloc(sizeof(float) * N_NODES * NHID);  // xW1 -> t -> outB
  float* h    = (float*)alloc(sizeof(float) * N_NODES * NHID);
  float* outA = (float*)alloc(sizeof(float) * N_NODES * NHID);
  float* Mm   = (float*)alloc(sizeof(float) * NHID * NHID);
  float* z    = (float*)alloc(sizeof(float) * N_NODES * NCLASS);
  int*   cols = (int*)  alloc(sizeof(int)   * N_NODES * CAP);
  float* vals = (float*)alloc(sizeof(float) * N_NODES * CAP);
  float* attn = (float*)alloc(sizeof(float) * N_NODES * CAP);
  int*   nnz  = (int*)  alloc(sizeof(int)   * N_NODES);
  float* xW1  = bufA;   // live: steps 1-3
  float* t    = bufA;   // live: steps 4-5 (xW1 dead after scan_build)
  float* outB = bufA;   // live: steps 6-7 (t dead after attn_crf1)

  const dim3 gg((N_NODES + 63) / 64, NHID / 64);  // (157, 4)

  // 1) xW1 = x @ W1
  gemm64<<<gg, 256, 0, stream>>>(x, W1, xW1, N_NODES, NFEAT, NHID);
  // 2) Mm = Wq @ Wk^T
  wqwkT<<<NHID, 256, 0, stream>>>(Wq, Wk, Mm);
  // 3) sorted CSR build + h = relu(adj @ xW1 + b1)
  scan_build<<<N_NODES, 256, 0, stream>>>(adj, xW1, b1, cols, vals, nnz, h);
  // 4) t = h @ Mm   (so score = t[i] . h[j]) — overwrites xW1 (dead)
  gemm64<<<gg, 256, 0, stream>>>(h, Mm, t, N_NODES, NHID, NHID);
  // 5) fused masked softmax + CRF iter 1 (h -> outA)
  attn_crf1<<<N_NODES, 256, 0, stream>>>(t, h, cols, nnz, attn, outA, al, be);
  // 6) CRF iter 2 (outA -> outB; overwrites t, dead)
  crf_iter<<<N_NODES, 256, 0, stream>>>(h, attn, cols, nnz, outA, outB, al, be);
  // 7) fused CRF iter 3 + LayerNorm + W2 (outB -> z)
  crf_ln_w2<<<N_NODES, 256, 0, stream>>>(h, attn, cols, nnz, outB, al, be,
                                         lnw, lnb, W2, z);
  // 8) y = adj @ z + b2, log_softmax
  final_k<<<N_NODES, 256, 0, stream>>>(z, vals, cols, nnz, b2, out);
}

// Round 11
// 840.233 us; speedup vs baseline: 1.0447x; 1.0447x over previous
//
#include <hip/hip_runtime.h>
#include <math.h>
#include <float.h>

#define N_NODES 10000
#define NFEAT   512
#define NHID    256
#define NCLASS  16
#define CAP     128   // max nnz/row; mean=51, sd=7.1 -> 128 is ~11 sigma
// N_NODES % 4 == 0, so 4-rows-per-block kernels need no row guard (grid 2500).

// native clang vector type — required by __builtin_nontemporal_load
// (HIP_vector_type float4 is a class and is rejected; see R6 compile error)
typedef float nfloat4 __attribute__((ext_vector_type(4)));

// ---------------- tiled f32 GEMM: C[M,N] = A[M,K] @ B[K,N] ----------------
// 64x64 tile, 256 threads, 4x4 microtile, KT=16.
__global__ __launch_bounds__(256) void gemm64(const float* __restrict__ A,
                                              const float* __restrict__ B,
                                              float* __restrict__ C,
                                              int M, int K, int N) {
  __shared__ float As[16][68];
  __shared__ float Bs[16][68];
  const int tid  = threadIdx.x;
  const int row0 = blockIdx.x * 64;
  const int col0 = blockIdx.y * 64;
  const int ty = tid >> 4, tx = tid & 15;
  const int arow = tid >> 2;
  const int akq  = (tid & 3) << 2;
  const int brow = tid >> 4;
  const int bcol = (tid & 15) << 2;

  float acc[4][4] = {};
  for (int k0 = 0; k0 < K; k0 += 16) {
    float4 av = make_float4(0.f, 0.f, 0.f, 0.f);
    const int gr = row0 + arow;
    if (gr < M) av = *(const float4*)&A[(size_t)gr * K + k0 + akq];
    As[akq + 0][arow] = av.x;
    As[akq + 1][arow] = av.y;
    As[akq + 2][arow] = av.z;
    As[akq + 3][arow] = av.w;
    const float4 bv = *(const float4*)&B[(size_t)(k0 + brow) * N + col0 + bcol];
    *(float4*)&Bs[brow][bcol] = bv;
    __syncthreads();
#pragma unroll
    for (int k = 0; k < 16; ++k) {
      const float4 a = *(const float4*)&As[k][ty << 2];
      const float4 b = *(const float4*)&Bs[k][tx << 2];
      acc[0][0] += a.x * b.x; acc[0][1] += a.x * b.y; acc[0][2] += a.x * b.z; acc[0][3] += a.x * b.w;
      acc[1][0] += a.y * b.x; acc[1][1] += a.y * b.y; acc[1][2] += a.y * b.z; acc[1][3] += a.y * b.w;
      acc[2][0] += a.z * b.x; acc[2][1] += a.z * b.y; acc[2][2] += a.z * b.z; acc[2][3] += a.z * b.w;
      acc[3][0] += a.w * b.x; acc[3][1] += a.w * b.y; acc[3][2] += a.w * b.z; acc[3][3] += a.w * b.w;
    }
    __syncthreads();
  }
#pragma unroll
  for (int j = 0; j < 4; ++j) {
    const int gr = row0 + (ty << 2) + j;
    if (gr < M) {
      const float4 o = make_float4(acc[j][0], acc[j][1], acc[j][2], acc[j][3]);
      *(float4*)&C[(size_t)gr * N + col0 + (tx << 2)] = o;
    }
  }
}

// ---------------- Mm = Wq @ Wk^T  (256x256) — float4 inner loop ----------
__global__ __launch_bounds__(256) void wqwkT(const float* __restrict__ Wq,
                                             const float* __restrict__ Wk,
                                             float* __restrict__ Mm) {
  __shared__ float4 qr4[NHID / 4];
  const int a = blockIdx.x, tid = threadIdx.x;
  if (tid < NHID / 4) qr4[tid] = ((const float4*)&Wq[(size_t)a * NHID])[tid];
  __syncthreads();
  const float4* kb = (const float4*)&Wk[(size_t)tid * NHID];
  float acc = 0.f;
#pragma unroll 8
  for (int c4 = 0; c4 < NHID / 4; ++c4) {
    const float4 k4 = kb[c4];
    const float4 q4 = qr4[c4];
    acc += q4.x * k4.x + q4.y * k4.y + q4.z * k4.z + q4.w * k4.w;
  }
  Mm[(size_t)a * NHID + tid] = acc;
}

// ------- scan adj row -> sorted CSR; fused h = relu(adj_sp @ xW1 + b1) ----
// adj is streamed nontemporal (read-once, keep xW1/h in cache). SpMM phase:
// edges split across 4 waves, float4 per lane, LDS partial combine.
__global__ __launch_bounds__(256) void scan_build(const float* __restrict__ adj,
                                                  const float* __restrict__ xW1,
                                                  const float* __restrict__ b1,
                                                  int* __restrict__ cols,
                                                  float* __restrict__ vals,
                                                  int* __restrict__ nnz,
                                                  float* __restrict__ h) {
  __shared__ int    lcols[CAP];
  __shared__ float  lvals[CAP];
  __shared__ int    scols[CAP];
  __shared__ float  svals[CAP];
  __shared__ float4 pacc[4][64];
  __shared__ int    cnt;
  const int row = blockIdx.x, tid = threadIdx.x;
  if (tid == 0) cnt = 0;
  __syncthreads();
  const nfloat4* arow = (const nfloat4*)&adj[(size_t)row * N_NODES];
  for (int v = tid; v < N_NODES / 4; v += 256) {
    const nfloat4 f = __builtin_nontemporal_load(&arow[v]);
    if (f.x != 0.f) { int p = atomicAdd(&cnt, 1); if (p < CAP) { lcols[p] = 4 * v + 0; lvals[p] = f.x; } }
    if (f.y != 0.f) { int p = atomicAdd(&cnt, 1); if (p < CAP) { lcols[p] = 4 * v + 1; lvals[p] = f.y; } }
    if (f.z != 0.f) { int p = atomicAdd(&cnt, 1); if (p < CAP) { lcols[p] = 4 * v + 2; lvals[p] = f.z; } }
    if (f.w != 0.f) { int p = atomicAdd(&cnt, 1); if (p < CAP) { lcols[p] = 4 * v + 3; lvals[p] = f.w; } }
  }
  __syncthreads();
  const int c = min(cnt, CAP);
  // parallel rank-sort (cols distinct) -> deterministic ascending order
  int myc = 0; float myv = 0.f; int rank = 0;
  if (tid < c) {
    myc = lcols[tid]; myv = lvals[tid];
    for (int e = 0; e < c; ++e) rank += (lcols[e] < myc);
  }
  __syncthreads();
  if (tid < c) { scols[rank] = myc; svals[rank] = myv; }
  __syncthreads();
  if (tid == 0) nnz[row] = c;
  if (tid < c) {
    cols[(size_t)row * CAP + tid] = scols[tid];
    vals[(size_t)row * CAP + tid] = svals[tid];
  }
  // SpMM: wave wv takes edges e = wv, wv+4, ...; lane owns features 4*lane..
  const int lane = tid & 63, wv = tid >> 6;
  float4 acc = make_float4(0.f, 0.f, 0.f, 0.f);
  for (int e = wv; e < c; e += 4) {
    const float vv = svals[e];
    const float4 xv = *(const float4*)&xW1[(size_t)scols[e] * NHID + (lane << 2)];
    acc.x += vv * xv.x; acc.y += vv * xv.y; acc.z += vv * xv.z; acc.w += vv * xv.w;
  }
  pacc[wv][lane] = acc;
  __syncthreads();
  if (wv == 0) {
    const float4 p0 = pacc[0][lane], p1 = pacc[1][lane];
    const float4 p2 = pacc[2][lane], p3 = pacc[3][lane];
    const float4 bb = *(const float4*)&b1[lane << 2];
    float4 r;
    r.x = fmaxf(bb.x + ((p0.x + p1.x) + (p2.x + p3.x)), 0.f);
    r.y = fmaxf(bb.y + ((p0.y + p1.y) + (p2.y + p3.y)), 0.f);
    r.z = fmaxf(bb.z + ((p0.z + p1.z) + (p2.z + p3.z)), 0.f);
    r.w = fmaxf(bb.w + ((p0.w + p1.w) + (p2.w + p3.w)), 0.f);
    *(float4*)&h[(size_t)row * NHID + (lane << 2)] = r;
  }
}

// ------- fused: scores + masked softmax + CRF iter 1 (outp == h) ----------
// 4 rows/block, wave-per-row. Scores: 16-lane groups, 4 edges in flight.
// Wave-local LDS (no cross-wave sharing) -> no __syncthreads needed.
__global__ __launch_bounds__(256) void attn_crf1(const float* __restrict__ t,
                                                 const float* __restrict__ h,
                                                 const int* __restrict__ cols,
                                                 const int* __restrict__ nnz,
                                                 float* __restrict__ attn,
                                                 float* __restrict__ outn,
                                                 const float* __restrict__ alpha_p,
                                                 const float* __restrict__ beta_p) {
  __shared__ int   lcols[4][CAP];
  __shared__ float sv[4][CAP];   // scores, then attn weights
  const int tid = threadIdx.x, lane = tid & 63, wv = tid >> 6;
  const int row = (blockIdx.x << 2) + wv;
  const int c = nnz[row];
  for (int e = lane; e < c; e += 64) lcols[wv][e] = cols[(size_t)row * CAP + e];
  const int gq = lane >> 4, gl = lane & 15;  // 4 groups x 16 lanes
  const float* tp = &t[(size_t)row * NHID + (gl << 2)];
  const float4 t0 = *(const float4*)&tp[0];
  const float4 t1 = *(const float4*)&tp[64];
  const float4 t2 = *(const float4*)&tp[128];
  const float4 t3 = *(const float4*)&tp[192];
  for (int e = gq; e < c; e += 4) {
    const float* hp = &h[(size_t)lcols[wv][e] * NHID + (gl << 2)];
    const float4 h0 = *(const float4*)&hp[0];
    const float4 h1 = *(const float4*)&hp[64];
    const float4 h2 = *(const float4*)&hp[128];
    const float4 h3 = *(const float4*)&hp[192];
    float p = t0.x * h0.x + t0.y * h0.y + t0.z * h0.z + t0.w * h0.w
            + t1.x * h1.x + t1.y * h1.y + t1.z * h1.z + t1.w * h1.w
            + t2.x * h2.x + t2.y * h2.y + t2.z * h2.z + t2.w * h2.w
            + t3.x * h3.x + t3.y * h3.y + t3.z * h3.z + t3.w * h3.w;
    p += __shfl_xor(p, 1, 64);
    p += __shfl_xor(p, 2, 64);
    p += __shfl_xor(p, 4, 64);
    p += __shfl_xor(p, 8, 64);
    if (gl == 0) sv[wv][e] = p * 0.0625f;  // 1/sqrt(256)
  }
  // softmax over <=128 edges, wave-parallel
  const float s1 = (lane      < c) ? sv[wv][lane]      : -FLT_MAX;
  const float s2 = (lane + 64 < c) ? sv[wv][lane + 64] : -FLT_MAX;
  float m = fmaxf(s1, s2);
#pragma unroll
  for (int o = 32; o > 0; o >>= 1) m = fmaxf(m, __shfl_xor(m, o, 64));
  const float e1 = (lane      < c) ? __expf(s1 - m) : 0.f;
  const float e2 = (lane + 64 < c) ? __expf(s2 - m) : 0.f;
  float sum = e1 + e2;
#pragma unroll
  for (int o = 32; o > 0; o >>= 1) sum += __shfl_xor(sum, o, 64);
  const float inv = 1.f / sum;
  if (lane < c) {
    const float aw = e1 * inv;
    sv[wv][lane] = aw;
    attn[(size_t)row * CAP + lane] = aw;
  }
  if (lane + 64 < c) {
    const float aw = e2 * inv;
    sv[wv][lane + 64] = aw;
    attn[(size_t)row * CAP + lane + 64] = aw;
  }
  // CRF iter 1 gather (outp == h), float4 per lane
  float4 acc = make_float4(0.f, 0.f, 0.f, 0.f);
  for (int e = 0; e < c; ++e) {
    const float ve = sv[wv][e];
    const float4 xv = *(const float4*)&h[(size_t)lcols[wv][e] * NHID + (lane << 2)];
    acc.x += ve * xv.x; acc.y += ve * xv.y; acc.z += ve * xv.z; acc.w += ve * xv.w;
  }
  const float a = alpha_p[0], b = beta_p[0];
  const float i2 = 1.f / (a + b);
  const float4 hq = *(const float4*)&h[(size_t)row * NHID + (lane << 2)];
  float4 o4;
  o4.x = (a * hq.x + b * acc.x) * i2;
  o4.y = (a * hq.y + b * acc.y) * i2;
  o4.z = (a * hq.z + b * acc.z) * i2;
  o4.w = (a * hq.w + b * acc.w) * i2;
  *(float4*)&outn[(size_t)row * NHID + (lane << 2)] = o4;
}

// ------- CRF mean-field iter, 4 rows/block wave-per-row, float4 gather ----
__global__ __launch_bounds__(256) void crf_iter(const float* __restrict__ h,
                                                const float* __restrict__ attn,
                                                const int* __restrict__ cols,
                                                const int* __restrict__ nnz,
                                                const float* __restrict__ outp,
                                                float* __restrict__ outn,
                                                const float* __restrict__ alpha_p,
                                                const float* __restrict__ beta_p) {
  __shared__ int   lcols[4][CAP];
  __shared__ float lv[4][CAP];
  const int tid = threadIdx.x, lane = tid & 63, wv = tid >> 6;
  const int row = (blockIdx.x << 2) + wv;
  const int c = nnz[row];
  for (int e = lane; e < c; e += 64) {
    lcols[wv][e] = cols[(size_t)row * CAP + e];
    lv[wv][e]   = attn[(size_t)row * CAP + e];
  }
  float4 acc = make_float4(0.f, 0.f, 0.f, 0.f);
  int e = 0;
  for (; e + 1 < c; e += 2) {
    const int   c0 = lcols[wv][e],   c1 = lcols[wv][e + 1];
    const float v0 = lv[wv][e],      v1 = lv[wv][e + 1];
    const float4 x0 = *(const float4*)&outp[(size_t)c0 * NHID + (lane << 2)];
    const float4 x1 = *(const float4*)&outp[(size_t)c1 * NHID + (lane << 2)];
    acc.x += v0 * x0.x; acc.y += v0 * x0.y; acc.z += v0 * x0.z; acc.w += v0 * x0.w;
    acc.x += v1 * x1.x; acc.y += v1 * x1.y; acc.z += v1 * x1.z; acc.w += v1 * x1.w;
  }
  if (e < c) {
    const float ve = lv[wv][e];
    const float4 xv = *(const float4*)&outp[(size_t)lcols[wv][e] * NHID + (lane << 2)];
    acc.x += ve * xv.x; acc.y += ve * xv.y; acc.z += ve * xv.z; acc.w += ve * xv.w;
  }
  const float a = alpha_p[0], b = beta_p[0];
  const float i2 = 1.f / (a + b);
  const float4 hq = *(const float4*)&h[(size_t)row * NHID + (lane << 2)];
  float4 o4;
  o4.x = (a * hq.x + b * acc.x) * i2;
  o4.y = (a * hq.y + b * acc.y) * i2;
  o4.z = (a * hq.z + b * acc.z) * i2;
  o4.w = (a * hq.w + b * acc.w) * i2;
  *(float4*)&outn[(size_t)row * NHID + (lane << 2)] = o4;
}

// ------- fused: CRF iter 3 + LayerNorm + z = v @ W2, 4 rows/block ---------
__global__ __launch_bounds__(256) void crf_ln_w2(const float* __restrict__ h,
                                                 const float* __restrict__ attn,
                                                 const int* __restrict__ cols,
                                                 const int* __restrict__ nnz,
                                                 const float* __restrict__ outp,
                                                 const float* __restrict__ alpha_p,
                                                 const float* __restrict__ beta_p,
                                                 const float* __restrict__ lnw,
                                                 const float* __restrict__ lnb,
                                                 const float* __restrict__ W2,
                                                 float* __restrict__ z) {
  __shared__ int   lcols[4][CAP];
  __shared__ float lv[4][CAP];
  __shared__ float vs[4][NHID];
  __shared__ float part[16][17];
  const int tid = threadIdx.x, lane = tid & 63, wv = tid >> 6;
  const int row = (blockIdx.x << 2) + wv;
  const int c = nnz[row];
  for (int e = lane; e < c; e += 64) {
    lcols[wv][e] = cols[(size_t)row * CAP + e];
    lv[wv][e]   = attn[(size_t)row * CAP + e];
  }
  float4 acc = make_float4(0.f, 0.f, 0.f, 0.f);
  for (int e = 0; e < c; ++e) {
    const float ve = lv[wv][e];
    const float4 xv = *(const float4*)&outp[(size_t)lcols[wv][e] * NHID + (lane << 2)];
    acc.x += ve * xv.x; acc.y += ve * xv.y; acc.z += ve * xv.z; acc.w += ve * xv.w;
  }
  const float a = alpha_p[0], b = beta_p[0];
  const float i2 = 1.f / (a + b);
  const float4 hq = *(const float4*)&h[(size_t)row * NHID + (lane << 2)];
  float4 x4;
  x4.x = (a * hq.x + b * acc.x) * i2;
  x4.y = (a * hq.y + b * acc.y) * i2;
  x4.z = (a * hq.z + b * acc.z) * i2;
  x4.w = (a * hq.w + b * acc.w) * i2;
  // LayerNorm (wave-wide stats over 256 features)
  float s = x4.x + x4.y + x4.z + x4.w;
#pragma unroll
  for (int o = 32; o > 0; o >>= 1) s += __shfl_xor(s, o, 64);
  const float mu = s * (1.f / NHID);
  float4 d4;
  d4.x = x4.x - mu; d4.y = x4.y - mu; d4.z = x4.z - mu; d4.w = x4.w - mu;
  float v = d4.x * d4.x + d4.y * d4.y + d4.z * d4.z + d4.w * d4.w;
#pragma unroll
  for (int o = 32; o > 0; o >>= 1) v += __shfl_xor(v, o, 64);
  const float rstd = rsqrtf(v * (1.f / NHID) + 1e-5f);
  const float4 lw = *(const float4*)&lnw[lane << 2];
  const float4 lb = *(const float4*)&lnb[lane << 2];
  float4 v4;
  v4.x = d4.x * rstd * lw.x + lb.x;
  v4.y = d4.y * rstd * lw.y + lb.y;
  v4.z = d4.z * rstd * lw.z + lb.z;
  v4.w = d4.w * rstd * lw.w + lb.w;
  *(float4*)&vs[wv][lane << 2] = v4;
  __syncthreads();
  // z = vs @ W2 for the block's 4 rows; W2 fragment register-cached
  const int g = tid >> 4, cc = tid & 15;
  float w2f[16];
#pragma unroll
  for (int u = 0; u < 16; ++u) w2f[u] = W2[(size_t)((g << 4) + u) * NCLASS + cc];
  for (int rr = 0; rr < 4; ++rr) {
    float p = 0.f;
#pragma unroll
    for (int u = 0; u < 16; ++u) p += vs[rr][(g << 4) + u] * w2f[u];
    part[g][cc] = p;
    __syncthreads();
    if (tid < NCLASS) {
      float q = 0.f;
#pragma unroll
      for (int g2 = 0; g2 < 16; ++g2) q += part[g2][tid];
      z[(size_t)((blockIdx.x << 2) + rr) * NCLASS + tid] = q;
    }
    __syncthreads();
  }
}

// ------- y = adj_sp @ z + b2, log_softmax; 4 rows/block wave-per-row ------
__global__ __launch_bounds__(256) void final_k(const float* __restrict__ z,
                                               const float* __restrict__ vals,
                                               const int* __restrict__ cols,
                                               const int* __restrict__ nnz,
                                               const float* __restrict__ b2,
                                               float* __restrict__ out) {
  __shared__ int   lcols[4][CAP];
  __shared__ float lv[4][CAP];
  const int tid = threadIdx.x, lane = tid & 63, wv = tid >> 6;
  const int row = (blockIdx.x << 2) + wv;
  const int c = nnz[row];
  for (int e = lane; e < c; e += 64) {
    lcols[wv][e] = cols[(size_t)row * CAP + e];
    lv[wv][e]   = vals[(size_t)row * CAP + e];
  }
  const int eg = lane >> 4, cc = lane & 15;  // 4 edge-groups x 16 classes
  float acc = 0.f;
  for (int e = eg; e < c; e += 4)
    acc += lv[wv][e] * z[(size_t)lcols[wv][e] * NCLASS + cc];
  acc += __shfl_xor(acc, 16, 64);
  acc += __shfl_xor(acc, 32, 64);
  const float y = acc + b2[cc];
  float m = y;
#pragma unroll
  for (int o = 8; o > 0; o >>= 1) m = fmaxf(m, __shfl_xor(m, o, 64));
  const float ev = __expf(y - m);
  float sme = ev;
#pragma unroll
  for (int o = 8; o > 0; o >>= 1) sme += __shfl_xor(sme, o, 64);
  if (eg == 0) out[(size_t)row * NCLASS + cc] = y - m - logf(sme);
}

extern "C" void kernel_launch(void* const* d_in, const int* in_sizes, int n_in,
                              void* d_out, int out_size, void* d_ws, size_t ws_size,
                              hipStream_t stream) {
  const float* x   = (const float*)d_in[0];
  const float* adj = (const float*)d_in[1];
  const float* W1  = (const float*)d_in[2];
  const float* b1  = (const float*)d_in[3];
  const float* Wq  = (const float*)d_in[4];
  const float* Wk  = (const float*)d_in[5];
  const float* al  = (const float*)d_in[6];
  const float* be  = (const float*)d_in[7];
  const float* lnw = (const float*)d_in[8];
  const float* lnb = (const float*)d_in[9];
  const float* W2  = (const float*)d_in[10];
  const float* b2  = (const float*)d_in[11];
  float* out = (float*)d_out;

  char* w = (char*)d_ws;
  size_t off = 0;
  auto alloc = [&](size_t bytes) -> void* {
    void* p = (void*)(w + off);
    off += (bytes + 255) & ~(size_t)255;
    return p;
  };
  float* bufA = (float*)alloc(sizeof(float) * N_NODES * NHID);  // xW1 -> t -> outB
  float* h    = (float*)alloc(sizeof(float) * N_NODES * NHID);
  float* outA = (float*)alloc(sizeof(float) * N_NODES * NHID);
  float* Mm   = (float*)alloc(sizeof(float) * NHID * NHID);
  float* z    = (float*)alloc(sizeof(float) * N_NODES * NCLASS);
  int*   cols = (int*)  alloc(sizeof(int)   * N_NODES * CAP);
  float* vals = (float*)alloc(sizeof(float) * N_NODES * CAP);
  float* attn = (float*)alloc(sizeof(float) * N_NODES * CAP);
  int*   nnz  = (int*)  alloc(sizeof(int)   * N_NODES);
  float* xW1  = bufA;   // live: steps 1-3
  float* t    = bufA;   // live: steps 4-5 (xW1 dead after scan_build)
  float* outB = bufA;   // live: steps 6-7 (t dead after attn_crf1)

  const dim3 gg((N_NODES + 63) / 64, NHID / 64);  // (157, 4)
  const int rb = N_NODES / 4;                      // 2500 blocks, 4 rows each

  // 1) xW1 = x @ W1
  gemm64<<<gg, 256, 0, stream>>>(x, W1, xW1, N_NODES, NFEAT, NHID);
  // 2) Mm = Wq @ Wk^T
  wqwkT<<<NHID, 256, 0, stream>>>(Wq, Wk, Mm);
  // 3) sorted CSR build + h = relu(adj @ xW1 + b1)
  scan_build<<<N_NODES, 256, 0, stream>>>(adj, xW1, b1, cols, vals, nnz, h);
  // 4) t = h @ Mm   (score = t[i] . h[j]) — overwrites xW1 (dead)
  gemm64<<<gg, 256, 0, stream>>>(h, Mm, t, N_NODES, NHID, NHID);
  // 5) fused masked softmax + CRF iter 1 (h -> outA)
  attn_crf1<<<rb, 256, 0, stream>>>(t, h, cols, nnz, attn, outA, al, be);
  // 6) CRF iter 2 (outA -> outB; overwrites t, dead)
  crf_iter<<<rb, 256, 0, stream>>>(h, attn, cols, nnz, outA, outB, al, be);
  // 7) fused CRF iter 3 + LayerNorm + W2 (outB -> z)
  crf_ln_w2<<<rb, 256, 0, stream>>>(h, attn, cols, nnz, outB, al, be,
                                    lnw, lnb, W2, z);
  // 8) y = adj @ z + b2, log_softmax
  final_k<<<rb, 256, 0, stream>>>(z, vals, cols, nnz, b2, out);
}

// Round 12
// 831.945 us; speedup vs baseline: 1.0551x; 1.0100x over previous
//
#include <hip/hip_runtime.h>
#include <math.h>
#include <float.h>

#define N_NODES 10000
#define NFEAT   512
#define NHID    256
#define NCLASS  16
#define CAP     128   // max nnz/row; mean=51, sd=7.1 -> 128 is ~11 sigma
// N_NODES % 4 == 0, so 4-rows-per-block kernels need no row guard (grid 2500).

// native clang vector type — required by __builtin_nontemporal_load
typedef float nfloat4 __attribute__((ext_vector_type(4)));

// ---------------- tiled f32 GEMM: C[M,N] = A[M,K] @ B[K,N] ----------------
__global__ __launch_bounds__(256) void gemm64(const float* __restrict__ A,
                                              const float* __restrict__ B,
                                              float* __restrict__ C,
                                              int M, int K, int N) {
  __shared__ float As[16][68];
  __shared__ float Bs[16][68];
  const int tid  = threadIdx.x;
  const int row0 = blockIdx.x * 64;
  const int col0 = blockIdx.y * 64;
  const int ty = tid >> 4, tx = tid & 15;
  const int arow = tid >> 2;
  const int akq  = (tid & 3) << 2;
  const int brow = tid >> 4;
  const int bcol = (tid & 15) << 2;

  float acc[4][4] = {};
  for (int k0 = 0; k0 < K; k0 += 16) {
    float4 av = make_float4(0.f, 0.f, 0.f, 0.f);
    const int gr = row0 + arow;
    if (gr < M) av = *(const float4*)&A[(size_t)gr * K + k0 + akq];
    As[akq + 0][arow] = av.x;
    As[akq + 1][arow] = av.y;
    As[akq + 2][arow] = av.z;
    As[akq + 3][arow] = av.w;
    const float4 bv = *(const float4*)&B[(size_t)(k0 + brow) * N + col0 + bcol];
    *(float4*)&Bs[brow][bcol] = bv;
    __syncthreads();
#pragma unroll
    for (int k = 0; k < 16; ++k) {
      const float4 a = *(const float4*)&As[k][ty << 2];
      const float4 b = *(const float4*)&Bs[k][tx << 2];
      acc[0][0] += a.x * b.x; acc[0][1] += a.x * b.y; acc[0][2] += a.x * b.z; acc[0][3] += a.x * b.w;
      acc[1][0] += a.y * b.x; acc[1][1] += a.y * b.y; acc[1][2] += a.y * b.z; acc[1][3] += a.y * b.w;
      acc[2][0] += a.z * b.x; acc[2][1] += a.z * b.y; acc[2][2] += a.z * b.z; acc[2][3] += a.z * b.w;
      acc[3][0] += a.w * b.x; acc[3][1] += a.w * b.y; acc[3][2] += a.w * b.z; acc[3][3] += a.w * b.w;
    }
    __syncthreads();
  }
#pragma unroll
  for (int j = 0; j < 4; ++j) {
    const int gr = row0 + (ty << 2) + j;
    if (gr < M) {
      const float4 o = make_float4(acc[j][0], acc[j][1], acc[j][2], acc[j][3]);
      *(float4*)&C[(size_t)gr * N + col0 + (tx << 2)] = o;
    }
  }
}

// ---------------- Mm = Wq @ Wk^T  (256x256) — float4 inner loop ----------
__global__ __launch_bounds__(256) void wqwkT(const float* __restrict__ Wq,
                                             const float* __restrict__ Wk,
                                             float* __restrict__ Mm) {
  __shared__ float4 qr4[NHID / 4];
  const int a = blockIdx.x, tid = threadIdx.x;
  if (tid < NHID / 4) qr4[tid] = ((const float4*)&Wq[(size_t)a * NHID])[tid];
  __syncthreads();
  const float4* kb = (const float4*)&Wk[(size_t)tid * NHID];
  float acc = 0.f;
#pragma unroll 8
  for (int c4 = 0; c4 < NHID / 4; ++c4) {
    const float4 k4 = kb[c4];
    const float4 q4 = qr4[c4];
    acc += q4.x * k4.x + q4.y * k4.y + q4.z * k4.z + q4.w * k4.w;
  }
  Mm[(size_t)a * NHID + tid] = acc;
}

// ------- scan adj row -> sorted CSR; fused h = relu(adj_sp @ xW1 + b1) ----
__global__ __launch_bounds__(256) void scan_build(const float* __restrict__ adj,
                                                  const float* __restrict__ xW1,
                                                  const float* __restrict__ b1,
                                                  int* __restrict__ cols,
                                                  float* __restrict__ vals,
                                                  int* __restrict__ nnz,
                                                  float* __restrict__ h) {
  __shared__ int    lcols[CAP];
  __shared__ float  lvals[CAP];
  __shared__ int    scols[CAP];
  __shared__ float  svals[CAP];
  __shared__ float4 pacc[4][64];
  __shared__ int    cnt;
  const int row = blockIdx.x, tid = threadIdx.x;
  if (tid == 0) cnt = 0;
  __syncthreads();
  const nfloat4* arow = (const nfloat4*)&adj[(size_t)row * N_NODES];
  for (int v = tid; v < N_NODES / 4; v += 256) {
    const nfloat4 f = __builtin_nontemporal_load(&arow[v]);
    if (f.x != 0.f) { int p = atomicAdd(&cnt, 1); if (p < CAP) { lcols[p] = 4 * v + 0; lvals[p] = f.x; } }
    if (f.y != 0.f) { int p = atomicAdd(&cnt, 1); if (p < CAP) { lcols[p] = 4 * v + 1; lvals[p] = f.y; } }
    if (f.z != 0.f) { int p = atomicAdd(&cnt, 1); if (p < CAP) { lcols[p] = 4 * v + 2; lvals[p] = f.z; } }
    if (f.w != 0.f) { int p = atomicAdd(&cnt, 1); if (p < CAP) { lcols[p] = 4 * v + 3; lvals[p] = f.w; } }
  }
  __syncthreads();
  const int c = min(cnt, CAP);
  // parallel rank-sort (cols distinct) -> deterministic ascending order
  int myc = 0; float myv = 0.f; int rank = 0;
  if (tid < c) {
    myc = lcols[tid]; myv = lvals[tid];
    for (int e = 0; e < c; ++e) rank += (lcols[e] < myc);
  }
  __syncthreads();
  if (tid < c) { scols[rank] = myc; svals[rank] = myv; }
  __syncthreads();
  if (tid == 0) nnz[row] = c;
  if (tid < c) {
    cols[(size_t)row * CAP + tid] = scols[tid];
    vals[(size_t)row * CAP + tid] = svals[tid];
  }
  // SpMM: wave wv takes edges e = wv, wv+4, ...; lane owns features 4*lane..
  const int lane = tid & 63, wv = tid >> 6;
  float4 acc = make_float4(0.f, 0.f, 0.f, 0.f);
  for (int e = wv; e < c; e += 4) {
    const float vv = svals[e];
    const float4 xv = *(const float4*)&xW1[(size_t)scols[e] * NHID + (lane << 2)];
    acc.x += vv * xv.x; acc.y += vv * xv.y; acc.z += vv * xv.z; acc.w += vv * xv.w;
  }
  pacc[wv][lane] = acc;
  __syncthreads();
  if (wv == 0) {
    const float4 p0 = pacc[0][lane], p1 = pacc[1][lane];
    const float4 p2 = pacc[2][lane], p3 = pacc[3][lane];
    const float4 bb = *(const float4*)&b1[lane << 2];
    float4 r;
    r.x = fmaxf(bb.x + ((p0.x + p1.x) + (p2.x + p3.x)), 0.f);
    r.y = fmaxf(bb.y + ((p0.y + p1.y) + (p2.y + p3.y)), 0.f);
    r.z = fmaxf(bb.z + ((p0.z + p1.z) + (p2.z + p3.z)), 0.f);
    r.w = fmaxf(bb.w + ((p0.w + p1.w) + (p2.w + p3.w)), 0.f);
    *(float4*)&h[(size_t)row * NHID + (lane << 2)] = r;
  }
}

// ------- fused: ONLINE-SOFTMAX scores + CRF iter 1 (single h-gather) ------
// R12 experiment: each edge's h[j] row is loaded ONCE (coalesced 1KB across
// 64 lanes) and used for BOTH the score dot and the running exp-weighted
// accumulation (flash-attention style running max/sum). Halves this kernel's
// gather traffic vs R11 (1044 -> 522 MB). Wave-per-row, 4 rows/block.
__global__ __launch_bounds__(256) void attn_crf1(const float* __restrict__ t,
                                                 const float* __restrict__ h,
                                                 const int* __restrict__ cols,
                                                 const int* __restrict__ nnz,
                                                 float* __restrict__ attn,
                                                 float* __restrict__ outn,
                                                 const float* __restrict__ alpha_p,
                                                 const float* __restrict__ beta_p) {
  __shared__ int   lcols[4][CAP];
  __shared__ float sv[4][CAP];   // raw scores (for attn-weight write-out)
  const int tid = threadIdx.x, lane = tid & 63, wv = tid >> 6;
  const int row = (blockIdx.x << 2) + wv;
  const int c = nnz[row];
  for (int e = lane; e < c; e += 64) lcols[wv][e] = cols[(size_t)row * CAP + e];
  // each lane owns 4 contiguous features of this row
  const float4 tq = *(const float4*)&t[(size_t)row * NHID + (lane << 2)];
  float m = -FLT_MAX, l = 0.f;
  float4 acc = make_float4(0.f, 0.f, 0.f, 0.f);
  for (int e = 0; e < c; ++e) {
    const float4 h4 = *(const float4*)&h[(size_t)lcols[wv][e] * NHID + (lane << 2)];
    // score: full-wave dot reduce (all 64 lanes -> same value everywhere)
    float p = tq.x * h4.x + tq.y * h4.y + tq.z * h4.z + tq.w * h4.w;
#pragma unroll
    for (int o = 1; o < 64; o <<= 1) p += __shfl_xor(p, o, 64);
    const float s = p * 0.0625f;  // 1/sqrt(256)
    if (lane == 0) sv[wv][e] = s;
    // online softmax update (uniform across wave)
    const float m_new = fmaxf(m, s);
    const float scale = __expf(m - m_new);
    const float w     = __expf(s - m_new);
    l = l * scale + w;
    acc.x = acc.x * scale + w * h4.x;
    acc.y = acc.y * scale + w * h4.y;
    acc.z = acc.z * scale + w * h4.z;
    acc.w = acc.w * scale + w * h4.w;
    m = m_new;
  }
  const float invl = 1.f / l;
  // write attn weights for crf iterations 2,3 (wave-local LDS, in-order)
  if (lane < c)      attn[(size_t)row * CAP + lane]      = __expf(sv[wv][lane]      - m) * invl;
  if (lane + 64 < c) attn[(size_t)row * CAP + lane + 64] = __expf(sv[wv][lane + 64] - m) * invl;
  // CRF iter 1: outn = (a*h + b*(attn@h)) / (a+b);  attn@h == acc/l
  const float a = alpha_p[0], b = beta_p[0];
  const float i2 = 1.f / (a + b);
  const float4 hq = *(const float4*)&h[(size_t)row * NHID + (lane << 2)];
  float4 o4;
  o4.x = (a * hq.x + b * acc.x * invl) * i2;
  o4.y = (a * hq.y + b * acc.y * invl) * i2;
  o4.z = (a * hq.z + b * acc.z * invl) * i2;
  o4.w = (a * hq.w + b * acc.w * invl) * i2;
  *(float4*)&outn[(size_t)row * NHID + (lane << 2)] = o4;
}

// ------- CRF mean-field iter, 4 rows/block wave-per-row, float4 gather ----
__global__ __launch_bounds__(256) void crf_iter(const float* __restrict__ h,
                                                const float* __restrict__ attn,
                                                const int* __restrict__ cols,
                                                const int* __restrict__ nnz,
                                                const float* __restrict__ outp,
                                                float* __restrict__ outn,
                                                const float* __restrict__ alpha_p,
                                                const float* __restrict__ beta_p) {
  __shared__ int   lcols[4][CAP];
  __shared__ float lv[4][CAP];
  const int tid = threadIdx.x, lane = tid & 63, wv = tid >> 6;
  const int row = (blockIdx.x << 2) + wv;
  const int c = nnz[row];
  for (int e = lane; e < c; e += 64) {
    lcols[wv][e] = cols[(size_t)row * CAP + e];
    lv[wv][e]   = attn[(size_t)row * CAP + e];
  }
  float4 acc = make_float4(0.f, 0.f, 0.f, 0.f);
  int e = 0;
  for (; e + 1 < c; e += 2) {
    const int   c0 = lcols[wv][e],   c1 = lcols[wv][e + 1];
    const float v0 = lv[wv][e],      v1 = lv[wv][e + 1];
    const float4 x0 = *(const float4*)&outp[(size_t)c0 * NHID + (lane << 2)];
    const float4 x1 = *(const float4*)&outp[(size_t)c1 * NHID + (lane << 2)];
    acc.x += v0 * x0.x; acc.y += v0 * x0.y; acc.z += v0 * x0.z; acc.w += v0 * x0.w;
    acc.x += v1 * x1.x; acc.y += v1 * x1.y; acc.z += v1 * x1.z; acc.w += v1 * x1.w;
  }
  if (e < c) {
    const float ve = lv[wv][e];
    const float4 xv = *(const float4*)&outp[(size_t)lcols[wv][e] * NHID + (lane << 2)];
    acc.x += ve * xv.x; acc.y += ve * xv.y; acc.z += ve * xv.z; acc.w += ve * xv.w;
  }
  const float a = alpha_p[0], b = beta_p[0];
  const float i2 = 1.f / (a + b);
  const float4 hq = *(const float4*)&h[(size_t)row * NHID + (lane << 2)];
  float4 o4;
  o4.x = (a * hq.x + b * acc.x) * i2;
  o4.y = (a * hq.y + b * acc.y) * i2;
  o4.z = (a * hq.z + b * acc.z) * i2;
  o4.w = (a * hq.w + b * acc.w) * i2;
  *(float4*)&outn[(size_t)row * NHID + (lane << 2)] = o4;
}

// ------- fused: CRF iter 3 + LayerNorm + z = v @ W2, 4 rows/block ---------
__global__ __launch_bounds__(256) void crf_ln_w2(const float* __restrict__ h,
                                                 const float* __restrict__ attn,
                                                 const int* __restrict__ cols,
                                                 const int* __restrict__ nnz,
                                                 const float* __restrict__ outp,
                                                 const float* __restrict__ alpha_p,
                                                 const float* __restrict__ beta_p,
                                                 const float* __restrict__ lnw,
                                                 const float* __restrict__ lnb,
                                                 const float* __restrict__ W2,
                                                 float* __restrict__ z) {
  __shared__ int   lcols[4][CAP];
  __shared__ float lv[4][CAP];
  __shared__ float vs[4][NHID];
  __shared__ float part[16][17];
  const int tid = threadIdx.x, lane = tid & 63, wv = tid >> 6;
  const int row = (blockIdx.x << 2) + wv;
  const int c = nnz[row];
  for (int e = lane; e < c; e += 64) {
    lcols[wv][e] = cols[(size_t)row * CAP + e];
    lv[wv][e]   = attn[(size_t)row * CAP + e];
  }
  float4 acc = make_float4(0.f, 0.f, 0.f, 0.f);
  for (int e = 0; e < c; ++e) {
    const float ve = lv[wv][e];
    const float4 xv = *(const float4*)&outp[(size_t)lcols[wv][e] * NHID + (lane << 2)];
    acc.x += ve * xv.x; acc.y += ve * xv.y; acc.z += ve * xv.z; acc.w += ve * xv.w;
  }
  const float a = alpha_p[0], b = beta_p[0];
  const float i2 = 1.f / (a + b);
  const float4 hq = *(const float4*)&h[(size_t)row * NHID + (lane << 2)];
  float4 x4;
  x4.x = (a * hq.x + b * acc.x) * i2;
  x4.y = (a * hq.y + b * acc.y) * i2;
  x4.z = (a * hq.z + b * acc.z) * i2;
  x4.w = (a * hq.w + b * acc.w) * i2;
  // LayerNorm (wave-wide stats over 256 features)
  float s = x4.x + x4.y + x4.z + x4.w;
#pragma unroll
  for (int o = 32; o > 0; o >>= 1) s += __shfl_xor(s, o, 64);
  const float mu = s * (1.f / NHID);
  float4 d4;
  d4.x = x4.x - mu; d4.y = x4.y - mu; d4.z = x4.z - mu; d4.w = x4.w - mu;
  float v = d4.x * d4.x + d4.y * d4.y + d4.z * d4.z + d4.w * d4.w;
#pragma unroll
  for (int o = 32; o > 0; o >>= 1) v += __shfl_xor(v, o, 64);
  const float rstd = rsqrtf(v * (1.f / NHID) + 1e-5f);
  const float4 lw = *(const float4*)&lnw[lane << 2];
  const float4 lb = *(const float4*)&lnb[lane << 2];
  float4 v4;
  v4.x = d4.x * rstd * lw.x + lb.x;
  v4.y = d4.y * rstd * lw.y + lb.y;
  v4.z = d4.z * rstd * lw.z + lb.z;
  v4.w = d4.w * rstd * lw.w + lb.w;
  *(float4*)&vs[wv][lane << 2] = v4;
  __syncthreads();
  // z = vs @ W2 for the block's 4 rows; W2 fragment register-cached
  const int g = tid >> 4, cc = tid & 15;
  float w2f[16];
#pragma unroll
  for (int u = 0; u < 16; ++u) w2f[u] = W2[(size_t)((g << 4) + u) * NCLASS + cc];
  for (int rr = 0; rr < 4; ++rr) {
    float p = 0.f;
#pragma unroll
    for (int u = 0; u < 16; ++u) p += vs[rr][(g << 4) + u] * w2f[u];
    part[g][cc] = p;
    __syncthreads();
    if (tid < NCLASS) {
      float q = 0.f;
#pragma unroll
      for (int g2 = 0; g2 < 16; ++g2) q += part[g2][tid];
      z[(size_t)((blockIdx.x << 2) + rr) * NCLASS + tid] = q;
    }
    __syncthreads();
  }
}

// ------- y = adj_sp @ z + b2, log_softmax; 4 rows/block wave-per-row ------
__global__ __launch_bounds__(256) void final_k(const float* __restrict__ z,
                                               const float* __restrict__ vals,
                                               const int* __restrict__ cols,
                                               const int* __restrict__ nnz,
                                               const float* __restrict__ b2,
                                               float* __restrict__ out) {
  __shared__ int   lcols[4][CAP];
  __shared__ float lv[4][CAP];
  const int tid = threadIdx.x, lane = tid & 63, wv = tid >> 6;
  const int row = (blockIdx.x << 2) + wv;
  const int c = nnz[row];
  for (int e = lane; e < c; e += 64) {
    lcols[wv][e] = cols[(size_t)row * CAP + e];
    lv[wv][e]   = vals[(size_t)row * CAP + e];
  }
  const int eg = lane >> 4, cc = lane & 15;  // 4 edge-groups x 16 classes
  float acc = 0.f;
  for (int e = eg; e < c; e += 4)
    acc += lv[wv][e] * z[(size_t)lcols[wv][e] * NCLASS + cc];
  acc += __shfl_xor(acc, 16, 64);
  acc += __shfl_xor(acc, 32, 64);
  const float y = acc + b2[cc];
  float m = y;
#pragma unroll
  for (int o = 8; o > 0; o >>= 1) m = fmaxf(m, __shfl_xor(m, o, 64));
  const float ev = __expf(y - m);
  float sme = ev;
#pragma unroll
  for (int o = 8; o > 0; o >>= 1) sme += __shfl_xor(sme, o, 64);
  if (eg == 0) out[(size_t)row * NCLASS + cc] = y - m - logf(sme);
}

extern "C" void kernel_launch(void* const* d_in, const int* in_sizes, int n_in,
                              void* d_out, int out_size, void* d_ws, size_t ws_size,
                              hipStream_t stream) {
  const float* x   = (const float*)d_in[0];
  const float* adj = (const float*)d_in[1];
  const float* W1  = (const float*)d_in[2];
  const float* b1  = (const float*)d_in[3];
  const float* Wq  = (const float*)d_in[4];
  const float* Wk  = (const float*)d_in[5];
  const float* al  = (const float*)d_in[6];
  const float* be  = (const float*)d_in[7];
  const float* lnw = (const float*)d_in[8];
  const float* lnb = (const float*)d_in[9];
  const float* W2  = (const float*)d_in[10];
  const float* b2  = (const float*)d_in[11];
  float* out = (float*)d_out;

  char* w = (char*)d_ws;
  size_t off = 0;
  auto alloc = [&](size_t bytes) -> void* {
    void* p = (void*)(w + off);
    off += (bytes + 255) & ~(size_t)255;
    return p;
  };
  float* bufA = (float*)alloc(sizeof(float) * N_NODES * NHID);  // xW1 -> t -> outB
  float* h    = (float*)alloc(sizeof(float) * N_NODES * NHID);
  float* outA = (float*)alloc(sizeof(float) * N_NODES * NHID);
  float* Mm   = (float*)alloc(sizeof(float) * NHID * NHID);
  float* z    = (float*)alloc(sizeof(float) * N_NODES * NCLASS);
  int*   cols = (int*)  alloc(sizeof(int)   * N_NODES * CAP);
  float* vals = (float*)alloc(sizeof(float) * N_NODES * CAP);
  float* attn = (float*)alloc(sizeof(float) * N_NODES * CAP);
  int*   nnz  = (int*)  alloc(sizeof(int)   * N_NODES);
  float* xW1  = bufA;   // live: steps 1-3
  float* t    = bufA;   // live: steps 4-5 (xW1 dead after scan_build)
  float* outB = bufA;   // live: steps 6-7 (t dead after attn_crf1)

  const dim3 gg((N_NODES + 63) / 64, NHID / 64);  // (157, 4)
  const int rb = N_NODES / 4;                      // 2500 blocks, 4 rows each

  // 1) xW1 = x @ W1
  gemm64<<<gg, 256, 0, stream>>>(x, W1, xW1, N_NODES, NFEAT, NHID);
  // 2) Mm = Wq @ Wk^T
  wqwkT<<<NHID, 256, 0, stream>>>(Wq, Wk, Mm);
  // 3) sorted CSR build + h = relu(adj @ xW1 + b1)
  scan_build<<<N_NODES, 256, 0, stream>>>(adj, xW1, b1, cols, vals, nnz, h);
  // 4) t = h @ Mm   (score = t[i] . h[j]) — overwrites xW1 (dead)
  gemm64<<<gg, 256, 0, stream>>>(h, Mm, t, N_NODES, NHID, NHID);
  // 5) fused ONLINE-softmax + CRF iter 1 (h -> outA), single h-gather
  attn_crf1<<<rb, 256, 0, stream>>>(t, h, cols, nnz, attn, outA, al, be);
  // 6) CRF iter 2 (outA -> outB; overwrites t, dead)
  crf_iter<<<rb, 256, 0, stream>>>(h, attn, cols, nnz, outA, outB, al, be);
  // 7) fused CRF iter 3 + LayerNorm + W2 (outB -> z)
  crf_ln_w2<<<rb, 256, 0, stream>>>(h, attn, cols, nnz, outB, al, be,
                                    lnw, lnb, W2, z);
  // 8) y = adj @ z + b2, log_softmax
  final_k<<<rb, 256, 0, stream>>>(z, vals, cols, nnz, b2, out);
}